// Round 2
// baseline (5584.436 us; speedup 1.0000x reference)
//
#include <hip/hip_runtime.h>
#include <hip/hip_bf16.h>
#include <math.h>

// Ernie4.5-VL MoE: router(top-6 of 64, dual branch) + experts + shared MLP.
// T=4096 H=1024 E=64 K=6, I_text=512 I_vis=256 I_shared=1024. All fp32 I/O.
// Expert/shared GEMMs in bf16 MFMA (fp32 accum); router in split-bf16 (hi/lo)
// for selection-grade precision. Intermediates (hsh, hbuf) stored bf16 —
// identical numerics to fp32 storage since GEMM2 stages A as bf16 anyway.

#define T_TOK 4096
#define HDIM  1024
#define NEXP  64
#define TOPK  6

typedef __attribute__((ext_vector_type(8))) short bf16x8;
typedef __attribute__((ext_vector_type(4))) float f32x4;

__device__ __forceinline__ unsigned short bf_rne(float f) {
  unsigned int u = __float_as_uint(f);
  u += 0x7FFFu + ((u >> 16) & 1u);
  return (unsigned short)(u >> 16);
}

// ---------------- prep: zero counters + detect mask dtype ----------------
__global__ void prep_kernel(const unsigned int* __restrict__ mask_words,
                            int* __restrict__ cnt, int* __restrict__ cursor,
                            int* __restrict__ flag) {
  int tid = threadIdx.x;                 // 128 threads
  cnt[tid] = 0; cursor[tid] = 0;
  __shared__ int ok;
  if (tid == 0) ok = 1;
  __syncthreads();
  int good = 1;
  #pragma unroll
  for (int j = 0; j < 8; j++) {
    unsigned int w = mask_words[tid * 8 + j];   // first 1024 words = 4096 B
    if (w & ~1u) good = 0;
  }
  if (!good) atomicAnd(&ok, 0);
  __syncthreads();
  if (tid == 0) *flag = ok;              // 1 -> int32 mask, 0 -> byte mask
}

// ---------------- router: logits[2][T][64] via split hi/lo bf16 MFMA ------
__global__ __launch_bounds__(256, 1)
void router_kernel(const float* __restrict__ x, const float* __restrict__ gwt,
                   const float* __restrict__ gwv, float* __restrict__ logits) {
  int z = blockIdx.z;
  const float* B = z ? gwv : gwt;
  int mt = blockIdx.x;                   // 64 blocks of 64 rows
  __shared__ __align__(16) unsigned short lAh[64][40], lAl[64][40];
  __shared__ __align__(16) unsigned short lBh[64][40], lBl[64][40];
  int tid = threadIdx.x;
  int wid = tid >> 6, lane = tid & 63;
  const float* srow = nullptr;
  unsigned short (*dh)[40] = nullptr; unsigned short (*dl)[40] = nullptr;
  int drow = 0;
  if (tid < 64) { srow = x + (size_t)(mt * 64 + tid) * HDIM; dh = lAh; dl = lAl; drow = tid; }
  else if (tid < 128) { srow = B + (size_t)(tid - 64) * HDIM; dh = lBh; dl = lBl; drow = tid - 64; }

  f32x4 acc[4];
  #pragma unroll
  for (int i = 0; i < 4; i++) { f32x4 zv = {0.f,0.f,0.f,0.f}; acc[i] = zv; }
  int lrow = lane & 15, lko = (lane >> 4) * 8;

  for (int k0 = 0; k0 < HDIM; k0 += 32) {
    if (srow) {
      const float4* p = (const float4*)(srow + k0);
      #pragma unroll
      for (int j = 0; j < 8; j++) {
        float4 v = p[j];
        unsigned int ux = __float_as_uint(v.x), uy = __float_as_uint(v.y);
        unsigned int uz = __float_as_uint(v.z), uw = __float_as_uint(v.w);
        unsigned short hx = ux >> 16, hy = uy >> 16, hz = uz >> 16, hw = uw >> 16;
        ushort4 hv = make_ushort4(hx, hy, hz, hw);
        ushort4 lv = make_ushort4(
            bf_rne(v.x - __uint_as_float((unsigned int)hx << 16)),
            bf_rne(v.y - __uint_as_float((unsigned int)hy << 16)),
            bf_rne(v.z - __uint_as_float((unsigned int)hz << 16)),
            bf_rne(v.w - __uint_as_float((unsigned int)hw << 16)));
        *(ushort4*)&dh[drow][j * 4] = hv;
        *(ushort4*)&dl[drow][j * 4] = lv;
      }
    }
    __syncthreads();
    bf16x8 ah = *(const bf16x8*)&lAh[wid * 16 + lrow][lko];
    bf16x8 al = *(const bf16x8*)&lAl[wid * 16 + lrow][lko];
    #pragma unroll
    for (int nf = 0; nf < 4; nf++) {
      bf16x8 bh = *(const bf16x8*)&lBh[nf * 16 + lrow][lko];
      bf16x8 bl = *(const bf16x8*)&lBl[nf * 16 + lrow][lko];
      acc[nf] = __builtin_amdgcn_mfma_f32_16x16x32_bf16(ah, bh, acc[nf], 0, 0, 0);
      acc[nf] = __builtin_amdgcn_mfma_f32_16x16x32_bf16(ah, bl, acc[nf], 0, 0, 0);
      acc[nf] = __builtin_amdgcn_mfma_f32_16x16x32_bf16(al, bh, acc[nf], 0, 0, 0);
    }
    __syncthreads();
  }
  int rbase = mt * 64 + wid * 16 + ((lane >> 4) << 2);
  #pragma unroll
  for (int nf = 0; nf < 4; nf++)
    #pragma unroll
    for (int j = 0; j < 4; j++) {
      int row = rbase + j;
      int col = nf * 16 + (lane & 15);
      logits[((size_t)z * T_TOK + row) * NEXP + col] = acc[nf][j];
    }
}

// ---------------- top-k: wave per token ----------------
__global__ __launch_bounds__(256)
void topk_kernel(const float* __restrict__ logits, const void* __restrict__ maskp,
                 const float* __restrict__ bias, const int* __restrict__ flag,
                 int* __restrict__ tbin, float* __restrict__ tw, int* __restrict__ cnt) {
  int tid = threadIdx.x;
  int tok = blockIdx.x * 4 + (tid >> 6);
  int lane = tid & 63;
  int vis;
  if (*flag) vis = ((const int*)maskp)[tok] != 0;
  else       vis = ((const unsigned char*)maskp)[tok] != 0;
  float l = logits[((size_t)(vis ? T_TOK : 0) + tok) * NEXP + lane];
  float m = l;
  #pragma unroll
  for (int o = 32; o; o >>= 1) m = fmaxf(m, __shfl_xor(m, o));
  float p = expf(l - m);
  float s = p;
  #pragma unroll
  for (int o = 32; o; o >>= 1) s += __shfl_xor(s, o);
  float prob = p / s;
  float score = prob + bias[vis * NEXP + lane];
  float sc = score, wsum = 0.f, myw = 0.f;
  int mybin = 0;
  for (int k = 0; k < TOPK; k++) {
    float v = sc; int idx = lane;
    #pragma unroll
    for (int o = 32; o; o >>= 1) {
      float v2 = __shfl_xor(v, o); int i2 = __shfl_xor(idx, o);
      if (v2 > v || (v2 == v && i2 < idx)) { v = v2; idx = i2; }
    }
    // after the butterfly every lane holds the winner (v, idx)
    float pw = __shfl(prob, idx);
    wsum += pw;
    if (lane == k) { mybin = vis * NEXP + idx; myw = pw; }
    if (lane == idx) sc = -INFINITY;
  }
  if (lane < TOPK) {
    tbin[tok * TOPK + lane] = mybin;
    tw[tok * TOPK + lane] = myw / wsum;
    atomicAdd(&cnt[mybin], 1);
  }
}

// ---------------- prefix scan over 128 bins ----------------
__global__ void prefix_kernel(const int* __restrict__ cnt, int* __restrict__ off) {
  __shared__ int s[128];
  int tid = threadIdx.x;
  s[tid] = cnt[tid];
  __syncthreads();
  for (int d = 1; d < 128; d <<= 1) {
    int v = (tid >= d) ? s[tid - d] : 0;
    __syncthreads();
    s[tid] += v;
    __syncthreads();
  }
  off[tid + 1] = s[tid];
  if (tid == 0) off[0] = 0;
}

// ---------------- scatter assignments to per-bin lists ----------------
__global__ void scatter_kernel(const int* __restrict__ tbin, const float* __restrict__ tw,
                               const int* __restrict__ off, int* __restrict__ cursor,
                               int* __restrict__ ptok, float* __restrict__ pw) {
  int i = blockIdx.x * 256 + threadIdx.x;
  if (i >= T_TOK * TOPK) return;
  int bin = tbin[i];
  int pos = atomicAdd(&cursor[bin], 1);
  int idx = off[bin] + pos;
  ptok[idx] = i / TOPK;
  pw[idx] = tw[i];
}

// ---------------- generic NT GEMM: C[M,N] = A[M,K] * B[N,K]^T ------------
// BM=256 (4 waves x 64 rows), BN=64 (x2 tiles when GU), BK=32, bf16 MFMA.
// GU: B has gate rows [0,I) and up rows [I,2I); epilogue writes bf16 silu(g)*u.
// GATHER: A rows via ptok (fp32 x). ABF: A is bf16 (intermediates).
// ATOMIC: epilogue does out[tok] += w * val.
template<bool GU, bool GATHER, bool ATOMIC, bool ABF, int BRANCH>
__global__ __launch_bounds__(256, 1)
void gemm_kernel(const void* __restrict__ A0, int lda,
                 const float* __restrict__ Bw, long bstride, int K, int I,
                 const int* __restrict__ off, const int* __restrict__ ptok,
                 const float* __restrict__ pw,
                 float* __restrict__ outp, int Mdense,
                 unsigned short* __restrict__ hbuf) {
  constexpr bool MOE = (BRANCH >= 0);
  int e = blockIdx.z, mt = blockIdx.x, nt = blockIdx.y;
  int base = 0, cnt = Mdense, off64v = 0;
  if (MOE) {
    int bin = (BRANCH == 1 ? NEXP : 0) + e;
    base = off[bin];
    cnt = off[bin + 1] - base;
    if (BRANCH == 1) off64v = off[NEXP];
  }
  if (mt * 256 >= cnt) return;
  const float* B = Bw + (size_t)e * (size_t)bstride;

  __shared__ __align__(16) unsigned short lA[256][40];
  __shared__ __align__(16) unsigned short lB[128][40];

  int tid = threadIdx.x;
  int rr = min(tid, cnt - mt * 256 - 1);
  size_t aoff;
  if constexpr (GATHER)   aoff = (size_t)ptok[base + mt * 256 + rr] * lda;
  else if constexpr (MOE) aoff = (size_t)off64v * 512 + (size_t)(base - off64v + mt * 256 + rr) * lda;
  else                    aoff = (size_t)(mt * 256 + rr) * lda;
  const float* arowf = (const float*)A0 + aoff;
  const unsigned short* arowb = (const unsigned short*)A0 + aoff;

  const int BNT = GU ? 128 : 64;
  const float* brow = nullptr;
  if (tid < BNT) {
    int r = (GU && tid >= 64) ? (I + nt * 64 + (tid - 64)) : (nt * 64 + tid);
    brow = B + (size_t)r * K;
  }

  f32x4 accg[4][4], accu[4][4];
  #pragma unroll
  for (int mf = 0; mf < 4; mf++)
    #pragma unroll
    for (int nf = 0; nf < 4; nf++) {
      f32x4 zv = {0.f, 0.f, 0.f, 0.f};
      accg[mf][nf] = zv;
      if constexpr (GU) accu[mf][nf] = zv;
    }

  int wid = tid >> 6, lane = tid & 63;
  int lrow = lane & 15, lko = (lane >> 4) * 8;

  for (int k0 = 0; k0 < K; k0 += 32) {
    if constexpr (ABF) {
      const uint4* p = (const uint4*)(arowb + k0);
      #pragma unroll
      for (int j = 0; j < 4; j++)
        *(uint4*)&lA[tid][j * 8] = p[j];
    } else {
      const float4* p = (const float4*)(arowf + k0);
      #pragma unroll
      for (int j = 0; j < 8; j++) {
        float4 v = p[j];
        *(ushort4*)&lA[tid][j * 4] =
            make_ushort4(bf_rne(v.x), bf_rne(v.y), bf_rne(v.z), bf_rne(v.w));
      }
    }
    if (tid < BNT) {
      const float4* q = (const float4*)(brow + k0);
      #pragma unroll
      for (int j = 0; j < 8; j++) {
        float4 v = q[j];
        *(ushort4*)&lB[tid][j * 4] =
            make_ushort4(bf_rne(v.x), bf_rne(v.y), bf_rne(v.z), bf_rne(v.w));
      }
    }
    __syncthreads();
    bf16x8 af[4];
    #pragma unroll
    for (int mf = 0; mf < 4; mf++)
      af[mf] = *(const bf16x8*)&lA[wid * 64 + mf * 16 + lrow][lko];
    #pragma unroll
    for (int nf = 0; nf < 4; nf++) {
      bf16x8 bg = *(const bf16x8*)&lB[nf * 16 + lrow][lko];
      #pragma unroll
      for (int mf = 0; mf < 4; mf++)
        accg[mf][nf] = __builtin_amdgcn_mfma_f32_16x16x32_bf16(af[mf], bg, accg[mf][nf], 0, 0, 0);
      if constexpr (GU) {
        bf16x8 bu = *(const bf16x8*)&lB[64 + nf * 16 + lrow][lko];
        #pragma unroll
        for (int mf = 0; mf < 4; mf++)
          accu[mf][nf] = __builtin_amdgcn_mfma_f32_16x16x32_bf16(af[mf], bu, accu[mf][nf], 0, 0, 0);
      }
    }
    __syncthreads();
  }

  int lc = lane & 15;
  #pragma unroll
  for (int mf = 0; mf < 4; mf++) {
    #pragma unroll
    for (int j = 0; j < 4; j++) {
      int r = wid * 64 + mf * 16 + ((lane >> 4) << 2) + j;
      int gm = mt * 256 + r;
      if (gm < cnt) {
        if constexpr (GU) {
          unsigned short* orow;
          if constexpr (MOE)
            orow = hbuf + (size_t)off64v * 512 + (size_t)(base - off64v + gm) * I + nt * 64;
          else
            orow = hbuf + (size_t)gm * I + nt * 64;
          #pragma unroll
          for (int nf = 0; nf < 4; nf++) {
            float g = accg[mf][nf][j], u = accu[mf][nf][j];
            orow[nf * 16 + lc] = bf_rne(g * u / (1.f + __expf(-g)));
          }
        } else if constexpr (ATOMIC) {
          int s = base + gm;
          int tokid = ptok[s];
          float w = pw[s];
          float* orow = outp + (size_t)tokid * HDIM + nt * 64;
          #pragma unroll
          for (int nf = 0; nf < 4; nf++)
            atomicAdd(&orow[nf * 16 + lc], accg[mf][nf][j] * w);
        } else {
          float* orow = outp + (size_t)gm * HDIM + nt * 64;
          #pragma unroll
          for (int nf = 0; nf < 4; nf++)
            orow[nf * 16 + lc] = accg[mf][nf][j];
        }
      }
    }
  }
}

// ---------------- launch ----------------
extern "C" void kernel_launch(void* const* d_in, const int* in_sizes, int n_in,
                              void* d_out, int out_size, void* d_ws, size_t ws_size,
                              hipStream_t stream) {
  const float* x    = (const float*)d_in[0];
  const void*  mask = d_in[1];
  const float* bias = (const float*)d_in[2];
  const float* gwt  = (const float*)d_in[3];
  const float* gwv  = (const float*)d_in[4];
  const float* tw13 = (const float*)d_in[5];
  const float* tw2  = (const float*)d_in[6];
  const float* vw13 = (const float*)d_in[7];
  const float* vw2  = (const float*)d_in[8];
  const float* sw13 = (const float*)d_in[9];
  const float* sw2  = (const float*)d_in[10];
  float* out = (float*)d_out;

  char* w = (char*)d_ws;
  auto alloc = [&](size_t bytes) { char* p = w; w += (bytes + 255) & ~(size_t)255; return p; };
  float* logits = (float*)alloc((size_t)2 * T_TOK * NEXP * 4);
  int*   tbin   = (int*)  alloc((size_t)T_TOK * TOPK * 4);
  float* twv    = (float*)alloc((size_t)T_TOK * TOPK * 4);
  int*   cnt    = (int*)  alloc(128 * 4);
  int*   off    = (int*)  alloc(129 * 4);
  int*   cursor = (int*)  alloc(128 * 4);
  int*   flag   = (int*)  alloc(4);
  int*   ptok   = (int*)  alloc((size_t)T_TOK * TOPK * 4);
  float* pwt    = (float*)alloc((size_t)T_TOK * TOPK * 4);
  unsigned short* hsh  = (unsigned short*)alloc((size_t)T_TOK * 1024 * 2);
  unsigned short* hbuf = (unsigned short*)alloc((size_t)T_TOK * TOPK * 512 * 2);
  (void)in_sizes; (void)n_in; (void)out_size; (void)ws_size;

  prep_kernel<<<1, 128, 0, stream>>>((const unsigned int*)mask, cnt, cursor, flag);
  router_kernel<<<dim3(64, 1, 2), 256, 0, stream>>>(x, gwt, gwv, logits);
  topk_kernel<<<T_TOK / 4, 256, 0, stream>>>(logits, mask, bias, flag, tbin, twv, cnt);
  prefix_kernel<<<1, 128, 0, stream>>>(cnt, off);
  scatter_kernel<<<(T_TOK * TOPK + 255) / 256, 256, 0, stream>>>(tbin, twv, off, cursor, ptok, pwt);

  // shared MLP: h = silu(g)*u (bf16), then out = h @ w2^T (out fully overwritten)
  gemm_kernel<true,  false, false, false, -1><<<dim3(16, 16, 1), 256, 0, stream>>>(
      x, HDIM, sw13, 0, HDIM, 1024, nullptr, nullptr, nullptr, nullptr, T_TOK, hsh);
  gemm_kernel<false, false, false, true,  -1><<<dim3(16, 16, 1), 256, 0, stream>>>(
      hsh, 1024, sw2, 0, 1024, 0, nullptr, nullptr, nullptr, out, T_TOK, nullptr);

  // expert GEMM1 (gathered x -> bf16 h slots)
  gemm_kernel<true, true, false, false, 0><<<dim3(16, 8, 64), 256, 0, stream>>>(
      x, HDIM, tw13, 1024 * 1024, HDIM, 512, off, ptok, pwt, nullptr, 0, hbuf);
  gemm_kernel<true, true, false, false, 1><<<dim3(16, 4, 64), 256, 0, stream>>>(
      x, HDIM, vw13, 512 * 1024, HDIM, 256, off, ptok, pwt, nullptr, 0, hbuf);

  // expert GEMM2 (bf16 h slots -> weighted atomic accumulate into out)
  gemm_kernel<false, false, true, true, 0><<<dim3(16, 16, 64), 256, 0, stream>>>(
      hbuf, 512, tw2, 1024 * 512, 512, 0, off, ptok, pwt, out, 0, nullptr);
  gemm_kernel<false, false, true, true, 1><<<dim3(16, 16, 64), 256, 0, stream>>>(
      hbuf, 256, vw2, 1024 * 256, 256, 0, off, ptok, pwt, out, 0, nullptr);
}